// Round 2
// baseline (1059.472 us; speedup 1.0000x reference)
//
#include <hip/hip_runtime.h>
#include <hip/hip_cooperative_groups.h>
#include <math.h>

namespace cg = cooperative_groups;

#define EPS 1e-6f

// ws layout (floats):
//   h      @ 0       [2][1024]
//   qkv    @ 2048    5 layers x [2][3072]   (q|k|v concatenated per row)
//   gu     @ 43008   5 layers x [2][2][4096] (gate/up)

__device__ __forceinline__ float red32(float v) {
#pragma unroll
    for (int m = 16; m >= 1; m >>= 1) v += __shfl_xor(v, m, 64);
    return v;
}

// ---------------- split-K GEMV phase with fused (deferred) RMSNorm ----------------
// out[z][s][Nslice] += rsqrt(mean(x^2)+eps) * ((x*nw) @ W) ; D fixed at 1024.
// tasks = nx*ny*nz, striped over the persistent grid.
template <int S, int R>
__device__ __forceinline__ void phase_gemv(
    float* smem, int t,
    const float* __restrict__ hbuf,   // [S][1024]
    const float* __restrict__ nw,     // [1024]
    const float* __restrict__ W0, const float* __restrict__ W1,
    const float* __restrict__ W2, size_t w_zstride,
    float* __restrict__ out, int out_sstride, int out_zstride, int N,
    int nx, int ny, int nz)
{
    float* xs = smem;                 // S*1024 (also reused as reduction scratch)
    float* sstot = smem + S * 1024;   // S*4
    const int lane = t & 63;
    const int dp = t >> 6;
    const int ntask = nx * ny * nz;

    for (int task = blockIdx.x; task < ntask; task += gridDim.x) {
        const int z = task / (nx * ny);
        const int rem = task - z * (nx * ny);
        const int by = rem / nx;
        const int bx = rem - by * nx;

        const float* W;
        if (W1) W = (z == 0) ? W0 : ((z == 1) ? W1 : W2);
        else    W = W0 + (size_t)z * w_zstride;
        float* outz = out + (size_t)z * out_zstride;

        const int j = bx * 256 + lane * 4;
        const int d0 = by * (4 * R) + dp * R;

        // 1) prefetch weight slab into registers (issued before anything else)
        float4 wreg[R];
        const float* Wp = W + (size_t)d0 * N + j;
#pragma unroll
        for (int i = 0; i < R; ++i)
            wreg[i] = *reinterpret_cast<const float4*>(Wp + (size_t)i * N);

        // 2) load x, apply nw, keep sum-of-squares in registers
        float ss[S];
        {
            float4 nw4 = *reinterpret_cast<const float4*>(nw + t * 4);
#pragma unroll
            for (int s = 0; s < S; ++s) {
                float4 xv = *reinterpret_cast<const float4*>(hbuf + s * 1024 + t * 4);
                ss[s] = xv.x * xv.x + xv.y * xv.y + xv.z * xv.z + xv.w * xv.w;
                float4 xw = make_float4(xv.x * nw4.x, xv.y * nw4.y, xv.z * nw4.z, xv.w * nw4.w);
                *reinterpret_cast<float4*>(&xs[s * 1024 + t * 4]) = xw;
            }
        }
        __syncthreads();

        // 3) dot product
        float acc[S][4];
#pragma unroll
        for (int s = 0; s < S; ++s) { acc[s][0] = acc[s][1] = acc[s][2] = acc[s][3] = 0.f; }
#pragma unroll
        for (int i = 0; i < R; ++i) {
            int dd = d0 + i;
#pragma unroll
            for (int s = 0; s < S; ++s) {
                float xv = xs[s * 1024 + dd];
                acc[s][0] += xv * wreg[i].x; acc[s][1] += xv * wreg[i].y;
                acc[s][2] += xv * wreg[i].z; acc[s][3] += xv * wreg[i].w;
            }
        }

        // 4) finish the rmsnorm sum (register/shuffle only)
#pragma unroll
        for (int s = 0; s < S; ++s) {
            float v = ss[s];
#pragma unroll
            for (int m = 32; m >= 1; m >>= 1) v += __shfl_xor(v, m, 64);
            if (lane == 0) sstot[s * 4 + dp] = v;
        }
        __syncthreads();   // xs reads done; sstot visible
        float sc[S];
#pragma unroll
        for (int s = 0; s < S; ++s) {
            float tot = sstot[s * 4 + 0] + sstot[s * 4 + 1] + sstot[s * 4 + 2] + sstot[s * 4 + 3];
            sc[s] = rsqrtf(tot / 1024.f + EPS);
        }

        // 5) cross-dp reduce + atomic add (reuse xs as scratch)
#pragma unroll
        for (int s = 0; s < S; ++s)
#pragma unroll
            for (int c = 0; c < 4; ++c)
                xs[(dp * S + s) * 256 + lane * 4 + c] = acc[s][c] * sc[s];
        __syncthreads();
        for (int o = t; o < S * 256; o += 256) {
            int s = o >> 8;
            int col = o & 255;
            float sum = 0.f;
#pragma unroll
            for (int p = 0; p < 4; ++p) sum += xs[(p * S + s) * 256 + col];
            atomicAdd(outz + (size_t)s * out_sstride + bx * 256 + col, sum);
        }
        __syncthreads();   // scratch reads done before next task rewrites xs
    }
}

// ---------------- fused attention + O-projection phase ----------------
// 512 tasks (4 x 128); every block redundantly recomputes the tiny 2x2
// attention with shuffle reductions (hidden under the Wo prefetch).
__device__ __forceinline__ void phase_attn_o(
    float* smem, int t,
    const float* __restrict__ qkv,   // [2][3072]
    const float* __restrict__ qnw, const float* __restrict__ knw,
    const float* __restrict__ W,     // Wo [1024][1024]
    float* __restrict__ out,         // h [2][1024]
    float* __restrict__ kvc)         // layer kv: k at 0, v at 2048
{
    float* xs = smem;                // 2048
    const int lane = t & 63;
    const int dp = t >> 6;

    for (int task = blockIdx.x; task < 512; task += gridDim.x) {
        const int bx = task & 3;
        const int by = task >> 2;
        const int j = bx * 256 + lane * 4;
        const int d0 = by * 8 + dp * 2;

        // 1) prefetch Wo slab
        float4 wreg[2];
        const float* Wp = W + (size_t)d0 * 1024 + j;
#pragma unroll
        for (int i = 0; i < 2; ++i)
            wreg[i] = *reinterpret_cast<const float4*>(Wp + (size_t)i * 1024);

        // 2) attention: head = t>>5, 32 lanes per head, d = g + c*32
        const int hh = t >> 5;
        const int g = t & 31;
        float q[2][4], k[2][4], v[2][4];
#pragma unroll
        for (int s = 0; s < 2; ++s)
#pragma unroll
            for (int c = 0; c < 4; ++c) {
                int d = g + c * 32;
                q[s][c] = qkv[s * 3072 +        hh * 128 + d];
                k[s][c] = qkv[s * 3072 + 1024 + hh * 128 + d];
                v[s][c] = qkv[s * 3072 + 2048 + hh * 128 + d];
            }
#pragma unroll
        for (int s = 0; s < 2; ++s) {
            float sq = q[s][0]*q[s][0] + q[s][1]*q[s][1] + q[s][2]*q[s][2] + q[s][3]*q[s][3];
            float sk = k[s][0]*k[s][0] + k[s][1]*k[s][1] + k[s][2]*k[s][2] + k[s][3]*k[s][3];
            sq = red32(sq); sk = red32(sk);
            float qsc = rsqrtf(sq / 128.f + EPS);
            float ksc = rsqrtf(sk / 128.f + EPS);
#pragma unroll
            for (int c = 0; c < 4; ++c) {
                q[s][c] *= qsc * qnw[g + c * 32];
                k[s][c] *= ksc * knw[g + c * 32];
            }
        }
        // RoPE: pos=0 identity; pos=1 angle = 10000^{-(d&63)/64}
        float inv0 = powf(10000.f, -(float)g / 64.f);
        float inv1 = powf(10000.f, -(float)(g + 32) / 64.f);
        float cA = cosf(inv0), sA = sinf(inv0);
        float cB = cosf(inv1), sB = sinf(inv1);
        float q1[4] = { q[1][0]*cA - q[1][2]*sA, q[1][1]*cB - q[1][3]*sB,
                        q[1][2]*cA + q[1][0]*sA, q[1][3]*cB + q[1][1]*sB };
        float k1[4] = { k[1][0]*cA - k[1][2]*sA, k[1][1]*cB - k[1][3]*sB,
                        k[1][2]*cA + k[1][0]*sA, k[1][3]*cB + k[1][1]*sB };

        if (task == 0) {
#pragma unroll
            for (int c = 0; c < 4; ++c) {
                int d = g + c * 32;
                kvc[hh * 256 +       d] = k[0][c];
                kvc[hh * 256 + 128 + d] = k1[c];
                kvc[2048 + hh * 256 +       d] = v[0][c];
                kvc[2048 + hh * 256 + 128 + d] = v[1][c];
            }
        }

        float p00 = red32(q[0][0]*k[0][0] + q[0][1]*k[0][1] + q[0][2]*k[0][2] + q[0][3]*k[0][3]);
        float p01 = red32(q[0][0]*k1[0]   + q[0][1]*k1[1]   + q[0][2]*k1[2]   + q[0][3]*k1[3]);
        float p10 = red32(q1[0]*k[0][0]   + q1[1]*k[0][1]   + q1[2]*k[0][2]   + q1[3]*k[0][3]);
        float p11 = red32(q1[0]*k1[0]     + q1[1]*k1[1]     + q1[2]*k1[2]     + q1[3]*k1[3]);

        const float scale = 0.08838834764831845f; // 1/sqrt(128)
        float s00 = p00 * scale, s01 = p01 * scale - 1e9f;
        float m0 = fmaxf(s00, s01);
        float e0 = expf(s00 - m0), e1 = expf(s01 - m0);
        float in0 = 1.f / (e0 + e1);
        float w00 = e0 * in0, w01 = e1 * in0;
        float s10 = p10 * scale, s11 = p11 * scale;
        float m1 = fmaxf(s10, s11);
        float f0 = expf(s10 - m1), f1 = expf(s11 - m1);
        float in1 = 1.f / (f0 + f1);
        float w10 = f0 * in1, w11 = f1 * in1;

#pragma unroll
        for (int c = 0; c < 4; ++c) {
            int d = g + c * 32;
            xs[       hh * 128 + d] = w00 * v[0][c] + w01 * v[1][c];
            xs[1024 + hh * 128 + d] = w10 * v[0][c] + w11 * v[1][c];
        }
        __syncthreads();

        // 3) O-projection dot
        float acc[2][4] = {{0.f,0.f,0.f,0.f},{0.f,0.f,0.f,0.f}};
#pragma unroll
        for (int i = 0; i < 2; ++i) {
            int dd = d0 + i;
#pragma unroll
            for (int s = 0; s < 2; ++s) {
                float xv = xs[s * 1024 + dd];
                acc[s][0] += xv * wreg[i].x; acc[s][1] += xv * wreg[i].y;
                acc[s][2] += xv * wreg[i].z; acc[s][3] += xv * wreg[i].w;
            }
        }
        __syncthreads();
#pragma unroll
        for (int s = 0; s < 2; ++s)
#pragma unroll
            for (int c = 0; c < 4; ++c)
                xs[(dp * 2 + s) * 256 + lane * 4 + c] = acc[s][c];
        __syncthreads();
        for (int o = t; o < 512; o += 256) {
            int s = o >> 8, col = o & 255;
            float sum = 0.f;
#pragma unroll
            for (int p = 0; p < 4; ++p) sum += xs[(p * 2 + s) * 256 + col];
            atomicAdd(out + (size_t)s * 1024 + bx * 256 + col, sum);
        }
        __syncthreads();
    }
}

// ---------------- down-proj phase with fused silu(gate)*up ----------------
// 512 tasks (4 x 128), 32 f-rows per task.
__device__ __forceinline__ void phase_down(
    float* smem, int t,
    const float* __restrict__ gu,  // [s][2][4096]
    const float* __restrict__ W,   // [4096][1024]
    float* __restrict__ out)       // h [2][1024]
{
    float* red = smem;             // 2048
    float* a   = smem + 2048;      // 2*32
    const int lane = t & 63;
    const int dp = t >> 6;

    for (int task = blockIdx.x; task < 512; task += gridDim.x) {
        const int bx = task & 3;
        const int by = task >> 2;
        const int j = bx * 256 + lane * 4;
        const int f0 = by * 32 + dp * 8;

        float4 wreg[8];
        const float* Wp = W + (size_t)f0 * 1024 + j;
#pragma unroll
        for (int i = 0; i < 8; ++i)
            wreg[i] = *reinterpret_cast<const float4*>(Wp + (size_t)i * 1024);

        if (t < 64) {
            int s = t >> 5, x = t & 31;
            int f = by * 32 + x;
            float g = gu[s * 8192 + f];
            float u = gu[s * 8192 + 4096 + f];
            a[s * 32 + x] = g / (1.f + expf(-g)) * u;
        }
        __syncthreads();

        float acc[2][4] = {{0.f,0.f,0.f,0.f},{0.f,0.f,0.f,0.f}};
#pragma unroll
        for (int i = 0; i < 8; ++i) {
            int dl = dp * 8 + i;
#pragma unroll
            for (int s = 0; s < 2; ++s) {
                float xv = a[s * 32 + dl];
                acc[s][0] += xv * wreg[i].x; acc[s][1] += xv * wreg[i].y;
                acc[s][2] += xv * wreg[i].z; acc[s][3] += xv * wreg[i].w;
            }
        }
        __syncthreads();
#pragma unroll
        for (int s = 0; s < 2; ++s)
#pragma unroll
            for (int c = 0; c < 4; ++c)
                red[(dp * 2 + s) * 256 + lane * 4 + c] = acc[s][c];
        __syncthreads();
        for (int o = t; o < 512; o += 256) {
            int s = o >> 8, col = o & 255;
            float sum = 0.f;
#pragma unroll
            for (int p = 0; p < 4; ++p) sum += red[(p * 2 + s) * 256 + col];
            atomicAdd(out + (size_t)s * 1024 + bx * 256 + col, sum);
        }
        __syncthreads();
    }
}

// ---------------- the whole network as one cooperative kernel ----------------
__global__ __launch_bounds__(256, 2) void net_kernel(
    const float* __restrict__ past_hidden,
    const int*   __restrict__ tok,
    const float* __restrict__ codec_emb,
    const float* __restrict__ Wq, const float* __restrict__ Wk,
    const float* __restrict__ Wv, const float* __restrict__ Wo,
    const float* __restrict__ qnw, const float* __restrict__ knw,
    const float* __restrict__ ln1, const float* __restrict__ ln2,
    const float* __restrict__ Wg, const float* __restrict__ Wu,
    const float* __restrict__ Wd, const float* __restrict__ fnw,
    const float* __restrict__ lmh,
    float* __restrict__ ws, float* __restrict__ logits, float* __restrict__ kvc)
{
    cg::grid_group grid = cg::this_grid();
    __shared__ float smem[2112];
    const int t = threadIdx.x;
    float* h    = ws;
    float* qkvb = ws + 2048;
    float* gub  = ws + 43008;

    // ---- init: zero accumulators, build h ----
    {
        const int gt = blockIdx.x * 256 + t;
        const int gs = gridDim.x * 256;
        for (int i = gt; i < 30720; i += gs) qkvb[i] = 0.f;
        for (int i = gt; i < 81920; i += gs) gub[i]  = 0.f;
        for (int i = gt; i < 30720; i += gs) logits[i] = 0.f;
        if (blockIdx.x == 0) {
            int tk = tok[0];
            for (int i = t; i < 1024; i += 256) {
                h[i]        = past_hidden[i];
                h[1024 + i] = codec_emb[(size_t)tk * 1024 + i];
            }
        }
    }
    grid.sync();

    for (int l = 0; l < 5; ++l) {
        const float* wq = Wq + (size_t)l * 1024 * 1024;
        const float* wk = Wk + (size_t)l * 1024 * 1024;
        const float* wv = Wv + (size_t)l * 1024 * 1024;
        const float* wo = Wo + (size_t)l * 1024 * 1024;
        const float* wg = Wg + (size_t)l * 1024 * 4096;
        const float* wu = Wu + (size_t)l * 1024 * 4096;
        const float* wd = Wd + (size_t)l * 4096 * 1024;
        float* qkv = qkvb + l * 6144;
        float* gu  = gub  + l * 16384;

        // QKV projection with deferred rmsnorm(ln1): 384 tasks
        phase_gemv<2, 8>(smem, t, h, ln1 + l * 1024, wq, wk, wv, 0,
                         qkv, 3072, 1024, 1024, 4, 32, 3);
        grid.sync();
        // attention fused into O projection; residual into h; kv cache write
        phase_attn_o(smem, t, qkv, qnw + l * 128, knw + l * 128, wo, h,
                     kvc + (size_t)(2 * l) * 2048);
        grid.sync();
        // gate & up with deferred rmsnorm(ln2): 512 tasks (R=16)
        phase_gemv<2, 16>(smem, t, h, ln2 + l * 1024, wg, wu, wu, 0,
                          gu, 8192, 4096, 4096, 16, 16, 2);
        grid.sync();
        // down proj with fused silu*up, residual into h: 512 tasks
        phase_down(smem, t, gu, wd, h);
        grid.sync();
    }

    // lm heads with fused (deferred) final rmsnorm: 1920 tasks
    phase_gemv<1, 16>(smem, t, h + 1024, fnw, lmh, nullptr, nullptr,
                      (size_t)1024 * 2048, logits, 2048, 2048, 2048,
                      8, 16, 15);
}

extern "C" void kernel_launch(void* const* d_in, const int* in_sizes, int n_in,
                              void* d_out, int out_size, void* d_ws, size_t ws_size,
                              hipStream_t stream)
{
    const float* past_hidden = (const float*)d_in[0];
    const int*   cb0         = (const int*)d_in[1];
    const float* codec_emb   = (const float*)d_in[2];
    const float* Wq  = (const float*)d_in[3];
    const float* Wk  = (const float*)d_in[4];
    const float* Wv  = (const float*)d_in[5];
    const float* Wo  = (const float*)d_in[6];
    const float* qnw = (const float*)d_in[7];
    const float* knw = (const float*)d_in[8];
    const float* ln1 = (const float*)d_in[9];
    const float* ln2 = (const float*)d_in[10];
    const float* Wg  = (const float*)d_in[11];
    const float* Wu  = (const float*)d_in[12];
    const float* Wd  = (const float*)d_in[13];
    const float* fnw = (const float*)d_in[14];
    const float* lmh = (const float*)d_in[15];

    float* ws     = (float*)d_ws;
    float* logits = (float*)d_out;
    float* kvc    = (float*)d_out + 30720;

    // grid sized for guaranteed co-residency: launch_bounds(256,2) => 2 blocks/CU
    static int nblk = 0;
    if (nblk == 0) {
        int perCU = 0;
        if (hipOccupancyMaxActiveBlocksPerMultiprocessor(&perCU, net_kernel, 256, 0) != hipSuccess
            || perCU < 1) perCU = 1;
        nblk = perCU * 256;
        if (nblk > 512) nblk = 512;
        if (nblk < 256) nblk = 256;
    }

    void* args[] = {
        (void*)&past_hidden, (void*)&cb0, (void*)&codec_emb,
        (void*)&Wq, (void*)&Wk, (void*)&Wv, (void*)&Wo,
        (void*)&qnw, (void*)&knw, (void*)&ln1, (void*)&ln2,
        (void*)&Wg, (void*)&Wu, (void*)&Wd, (void*)&fnw, (void*)&lmh,
        (void*)&ws, (void*)&logits, (void*)&kvc
    };
    hipLaunchCooperativeKernel((void*)net_kernel, dim3(nblk), dim3(256),
                               args, 0, stream);
}

// Round 4
// 740.180 us; speedup vs baseline: 1.4314x; 1.4314x over previous
//
#include <hip/hip_runtime.h>
#include <math.h>

#define EPS 1e-6f
#define FLAGS_OFF 124928   // int flags live at ws + FLAGS_OFF (floats)

// ws layout (floats):
//   h      @ 0       [2][1024]            (in-place residual accumulation, atomics only)
//   qkv    @ 2048    5 layers x [2][3072]
//   gu     @ 43008   5 layers x [2][2][4096]
//   flags  @ 124928  32 ints (per-phase done counters)

// Coherence-point load (agent scope): always fresh across XCDs, never hoisted by LICM.
__device__ __forceinline__ float ato(const float* p) {
    return __hip_atomic_load(p, __ATOMIC_RELAXED, __HIP_MEMORY_SCOPE_AGENT);
}

__device__ __forceinline__ float red32(float v) {
#pragma unroll
    for (int m = 16; m >= 1; m >>= 1) v += __shfl_xor(v, m, 64);
    return v;
}

// Consumer side: spin on producer's done-counter. Called AFTER weight prefetch is issued.
__device__ __forceinline__ void spin_wait(int* flags, int idx, int need, int t) {
    if (t == 0) {
        while (__hip_atomic_load(&flags[idx], __ATOMIC_RELAXED, __HIP_MEMORY_SCOPE_AGENT) < need)
            __builtin_amdgcn_s_sleep(16);
    }
    __syncthreads();
}

// Producer side: drain this wave's vmem (output atomics), barrier (drains all waves),
// then bump the phase counter. The barrier also protects LDS scratch reuse.
__device__ __forceinline__ void task_done(int* flags, int idx, int t) {
    asm volatile("s_waitcnt vmcnt(0)" ::: "memory");
    __syncthreads();
    if (t == 0) __hip_atomic_fetch_add(&flags[idx], 1, __ATOMIC_RELAXED, __HIP_MEMORY_SCOPE_AGENT);
}

// ---------------- init: zero accumulators + flags, build h ----------------
__global__ void init_kernel(const float* __restrict__ past_hidden,
                            const float* __restrict__ codec_emb,
                            const int* __restrict__ tok,
                            float* __restrict__ ws,
                            float* __restrict__ logits)
{
    size_t idx = (size_t)blockIdx.x * blockDim.x + threadIdx.x;
    size_t stride = (size_t)gridDim.x * blockDim.x;
    for (size_t i = idx; i < 30720; i += stride) ws[2048 + i] = 0.f;   // qkv x5
    for (size_t i = idx; i < 81920; i += stride) ws[43008 + i] = 0.f;  // gu x5
    for (size_t i = idx; i < 30720; i += stride) logits[i] = 0.f;
    if (idx < 32) ((int*)(ws + FLAGS_OFF))[idx] = 0;
    int t = tok[0];
    for (size_t i = idx; i < 1024; i += stride) {
        ws[i]        = past_hidden[i];
        ws[1024 + i] = codec_emb[(size_t)t * 1024 + i];
    }
}

// ---------------- split-K GEMV phase, deferred RMSNorm, flag-synced ----------------
// out[z][s][Nslice] += rsqrt(mean(x^2)+eps) * ((x*nw) @ W) ; D = 1024.
template <int S, int R>
__device__ void phase_gemv(
    float* smem, int t,
    const float* __restrict__ hbuf,   // [S][1024], read via ato()
    const float* __restrict__ nw,     // [1024]
    const float* __restrict__ W0, const float* __restrict__ W1,
    const float* __restrict__ W2, size_t w_zstride,
    float* __restrict__ out, int out_sstride, size_t out_zstride, int N,
    int nx, int ny, int nz,
    int* flags, int widx, int wneed, int didx)
{
    float* xs = smem;                 // S*1024, reused as reduction scratch
    float* sstot = smem + S * 1024;   // S*4
    const int lane = t & 63;
    const int dp = t >> 6;
    const int ntask = nx * ny * nz;
    bool waited = (widx < 0);

    for (int task = blockIdx.x; task < ntask; task += gridDim.x) {
        const int z = task / (nx * ny);
        const int rem = task - z * (nx * ny);
        const int by = rem / nx;
        const int bx = rem - by * nx;

        const float* W;
        if (W1) W = (z == 0) ? W0 : ((z == 1) ? W1 : W2);
        else    W = W0 + (size_t)z * w_zstride;
        float* outz = out + (size_t)z * out_zstride;

        const int j = bx * 256 + lane * 4;
        const int d0 = by * (4 * R) + dp * R;

        // 1) issue weight prefetch BEFORE waiting on the dependency
        float4 wreg[R];
        const float* Wp = W + (size_t)d0 * N + j;
#pragma unroll
        for (int i = 0; i < R; ++i)
            wreg[i] = *reinterpret_cast<const float4*>(Wp + (size_t)i * N);

        if (!waited) { spin_wait(flags, widx, wneed, t); waited = true; }

        // 2) gather x at the coherence point, apply nw, keep sum-of-squares
        float ss[S];
        {
            float4 nw4 = *reinterpret_cast<const float4*>(nw + t * 4);
#pragma unroll
            for (int s = 0; s < S; ++s) {
                float x0 = ato(hbuf + s * 1024 + t * 4 + 0);
                float x1 = ato(hbuf + s * 1024 + t * 4 + 1);
                float x2 = ato(hbuf + s * 1024 + t * 4 + 2);
                float x3 = ato(hbuf + s * 1024 + t * 4 + 3);
                ss[s] = x0 * x0 + x1 * x1 + x2 * x2 + x3 * x3;
                xs[s * 1024 + t * 4 + 0] = x0 * nw4.x;
                xs[s * 1024 + t * 4 + 1] = x1 * nw4.y;
                xs[s * 1024 + t * 4 + 2] = x2 * nw4.z;
                xs[s * 1024 + t * 4 + 3] = x3 * nw4.w;
            }
        }
        __syncthreads();

        // 3) dot product
        float acc[S][4];
#pragma unroll
        for (int s = 0; s < S; ++s) { acc[s][0] = acc[s][1] = acc[s][2] = acc[s][3] = 0.f; }
#pragma unroll
        for (int i = 0; i < R; ++i) {
            int dd = d0 + i;
#pragma unroll
            for (int s = 0; s < S; ++s) {
                float xv = xs[s * 1024 + dd];
                acc[s][0] += xv * wreg[i].x; acc[s][1] += xv * wreg[i].y;
                acc[s][2] += xv * wreg[i].z; acc[s][3] += xv * wreg[i].w;
            }
        }

        // 4) finish rmsnorm sum (shuffle only)
#pragma unroll
        for (int s = 0; s < S; ++s) {
            float v = ss[s];
#pragma unroll
            for (int m = 32; m >= 1; m >>= 1) v += __shfl_xor(v, m, 64);
            if (lane == 0) sstot[s * 4 + dp] = v;
        }
        __syncthreads();
        float sc[S];
#pragma unroll
        for (int s = 0; s < S; ++s) {
            float tot = sstot[s * 4 + 0] + sstot[s * 4 + 1] + sstot[s * 4 + 2] + sstot[s * 4 + 3];
            sc[s] = rsqrtf(tot / 1024.f + EPS);
        }

        // 5) cross-dp reduce + atomic add
#pragma unroll
        for (int s = 0; s < S; ++s)
#pragma unroll
            for (int c = 0; c < 4; ++c)
                xs[(dp * S + s) * 256 + lane * 4 + c] = acc[s][c] * sc[s];
        __syncthreads();
        for (int o = t; o < S * 256; o += 256) {
            int s = o >> 8;
            int col = o & 255;
            float sum = 0.f;
#pragma unroll
            for (int p = 0; p < 4; ++p) sum += xs[(p * S + s) * 256 + col];
            atomicAdd(outz + (size_t)s * out_sstride + bx * 256 + col, sum);
        }
        task_done(flags, didx, t);
    }
}

// ---------------- fused attention + O-projection phase (512 tasks) ----------------
__device__ void phase_attn_o(
    float* smem, int t,
    const float* __restrict__ qkv, const float* __restrict__ qnw,
    const float* __restrict__ knw, const float* __restrict__ W,
    float* __restrict__ out, float* __restrict__ kvc,
    int* flags, int widx, int wneed, int didx)
{
    float* xs = smem;                // 2048
    const int lane = t & 63;
    const int dp = t >> 6;
    bool waited = false;

    for (int task = blockIdx.x; task < 512; task += gridDim.x) {
        const int bx = task & 3;
        const int by = task >> 2;
        const int j = bx * 256 + lane * 4;
        const int d0 = by * 8 + dp * 2;

        float4 wreg[2];
        const float* Wp = W + (size_t)d0 * 1024 + j;
        wreg[0] = *reinterpret_cast<const float4*>(Wp);
        wreg[1] = *reinterpret_cast<const float4*>(Wp + 1024);

        if (!waited) { spin_wait(flags, widx, wneed, t); waited = true; }

        const int hh = t >> 5;
        const int g = t & 31;
        float q[2][4], k[2][4], v[2][4];
#pragma unroll
        for (int s = 0; s < 2; ++s)
#pragma unroll
            for (int c = 0; c < 4; ++c) {
                int d = g + c * 32;
                q[s][c] = ato(qkv + s * 3072 +        hh * 128 + d);
                k[s][c] = ato(qkv + s * 3072 + 1024 + hh * 128 + d);
                v[s][c] = ato(qkv + s * 3072 + 2048 + hh * 128 + d);
            }
#pragma unroll
        for (int s = 0; s < 2; ++s) {
            float sq = q[s][0]*q[s][0] + q[s][1]*q[s][1] + q[s][2]*q[s][2] + q[s][3]*q[s][3];
            float sk = k[s][0]*k[s][0] + k[s][1]*k[s][1] + k[s][2]*k[s][2] + k[s][3]*k[s][3];
            sq = red32(sq); sk = red32(sk);
            float qsc = rsqrtf(sq / 128.f + EPS);
            float ksc = rsqrtf(sk / 128.f + EPS);
#pragma unroll
            for (int c = 0; c < 4; ++c) {
                q[s][c] *= qsc * qnw[g + c * 32];
                k[s][c] *= ksc * knw[g + c * 32];
            }
        }
        float inv0 = powf(10000.f, -(float)g / 64.f);
        float inv1 = powf(10000.f, -(float)(g + 32) / 64.f);
        float cA = cosf(inv0), sA = sinf(inv0);
        float cB = cosf(inv1), sB = sinf(inv1);
        float q1[4] = { q[1][0]*cA - q[1][2]*sA, q[1][1]*cB - q[1][3]*sB,
                        q[1][2]*cA + q[1][0]*sA, q[1][3]*cB + q[1][1]*sB };
        float k1[4] = { k[1][0]*cA - k[1][2]*sA, k[1][1]*cB - k[1][3]*sB,
                        k[1][2]*cA + k[1][0]*sA, k[1][3]*cB + k[1][1]*sB };

        if (task == 0) {
#pragma unroll
            for (int c = 0; c < 4; ++c) {
                int d = g + c * 32;
                kvc[hh * 256 +       d] = k[0][c];
                kvc[hh * 256 + 128 + d] = k1[c];
                kvc[2048 + hh * 256 +       d] = v[0][c];
                kvc[2048 + hh * 256 + 128 + d] = v[1][c];
            }
        }

        float p00 = red32(q[0][0]*k[0][0] + q[0][1]*k[0][1] + q[0][2]*k[0][2] + q[0][3]*k[0][3]);
        float p01 = red32(q[0][0]*k1[0]   + q[0][1]*k1[1]   + q[0][2]*k1[2]   + q[0][3]*k1[3]);
        float p10 = red32(q1[0]*k[0][0]   + q1[1]*k[0][1]   + q1[2]*k[0][2]   + q1[3]*k[0][3]);
        float p11 = red32(q1[0]*k1[0]     + q1[1]*k1[1]     + q1[2]*k1[2]     + q1[3]*k1[3]);

        const float scale = 0.08838834764831845f; // 1/sqrt(128)
        float s00 = p00 * scale, s01 = p01 * scale - 1e9f;
        float m0 = fmaxf(s00, s01);
        float e0 = expf(s00 - m0), e1 = expf(s01 - m0);
        float in0 = 1.f / (e0 + e1);
        float w00 = e0 * in0, w01 = e1 * in0;
        float s10 = p10 * scale, s11 = p11 * scale;
        float m1 = fmaxf(s10, s11);
        float f0 = expf(s10 - m1), f1 = expf(s11 - m1);
        float in1 = 1.f / (f0 + f1);
        float w10 = f0 * in1, w11 = f1 * in1;

#pragma unroll
        for (int c = 0; c < 4; ++c) {
            int d = g + c * 32;
            xs[       hh * 128 + d] = w00 * v[0][c] + w01 * v[1][c];
            xs[1024 + hh * 128 + d] = w10 * v[0][c] + w11 * v[1][c];
        }
        __syncthreads();

        float acc[2][4] = {{0.f,0.f,0.f,0.f},{0.f,0.f,0.f,0.f}};
#pragma unroll
        for (int i = 0; i < 2; ++i) {
            int dd = d0 + i;
#pragma unroll
            for (int s = 0; s < 2; ++s) {
                float xv = xs[s * 1024 + dd];
                acc[s][0] += xv * wreg[i].x; acc[s][1] += xv * wreg[i].y;
                acc[s][2] += xv * wreg[i].z; acc[s][3] += xv * wreg[i].w;
            }
        }
        __syncthreads();
#pragma unroll
        for (int s = 0; s < 2; ++s)
#pragma unroll
            for (int c = 0; c < 4; ++c)
                xs[(dp * 2 + s) * 256 + lane * 4 + c] = acc[s][c];
        __syncthreads();
        for (int o = t; o < 512; o += 256) {
            int s = o >> 8, col = o & 255;
            float sum = 0.f;
#pragma unroll
            for (int p = 0; p < 4; ++p) sum += xs[(p * 2 + s) * 256 + col];
            atomicAdd(out + (size_t)s * 1024 + bx * 256 + col, sum);
        }
        task_done(flags, didx, t);
    }
}

// ---------------- down-proj phase with fused silu(gate)*up (512 tasks) ----------------
__device__ void phase_down(
    float* smem, int t,
    const float* __restrict__ gu, const float* __restrict__ W,
    float* __restrict__ out,
    int* flags, int widx, int wneed, int didx)
{
    float* red = smem;             // 2048
    float* a   = smem + 2048;      // 2*32
    const int lane = t & 63;
    const int dp = t >> 6;
    bool waited = false;

    for (int task = blockIdx.x; task < 512; task += gridDim.x) {
        const int bx = task & 3;
        const int by = task >> 2;
        const int j = bx * 256 + lane * 4;
        const int f0 = by * 32 + dp * 8;

        float4 wreg[8];
        const float* Wp = W + (size_t)f0 * 1024 + j;
#pragma unroll
        for (int i = 0; i < 8; ++i)
            wreg[i] = *reinterpret_cast<const float4*>(Wp + (size_t)i * 1024);

        if (!waited) { spin_wait(flags, widx, wneed, t); waited = true; }

        if (t < 64) {
            int s = t >> 5, x = t & 31;
            int f = by * 32 + x;
            float g = ato(gu + s * 8192 + f);
            float u = ato(gu + s * 8192 + 4096 + f);
            a[s * 32 + x] = g / (1.f + expf(-g)) * u;
        }
        __syncthreads();

        float acc[2][4] = {{0.f,0.f,0.f,0.f},{0.f,0.f,0.f,0.f}};
#pragma unroll
        for (int i = 0; i < 8; ++i) {
            int dl = dp * 8 + i;
#pragma unroll
            for (int s = 0; s < 2; ++s) {
                float xv = a[s * 32 + dl];
                acc[s][0] += xv * wreg[i].x; acc[s][1] += xv * wreg[i].y;
                acc[s][2] += xv * wreg[i].z; acc[s][3] += xv * wreg[i].w;
            }
        }
        __syncthreads();
#pragma unroll
        for (int s = 0; s < 2; ++s)
#pragma unroll
            for (int c = 0; c < 4; ++c)
                red[(dp * 2 + s) * 256 + lane * 4 + c] = acc[s][c];
        __syncthreads();
        for (int o = t; o < 512; o += 256) {
            int s = o >> 8, col = o & 255;
            float sum = 0.f;
#pragma unroll
            for (int p = 0; p < 4; ++p) sum += red[(p * 2 + s) * 256 + col];
            atomicAdd(out + (size_t)s * 1024 + bx * 256 + col, sum);
        }
        task_done(flags, didx, t);
    }
}

// ---------------- whole network, one persistent kernel, flag-pipelined ----------------
__global__ __launch_bounds__(256, 4) void net_kernel(
    const float* __restrict__ Wq, const float* __restrict__ Wk,
    const float* __restrict__ Wv, const float* __restrict__ Wo,
    const float* __restrict__ qnw, const float* __restrict__ knw,
    const float* __restrict__ ln1, const float* __restrict__ ln2,
    const float* __restrict__ Wg, const float* __restrict__ Wu,
    const float* __restrict__ Wd, const float* __restrict__ fnw,
    const float* __restrict__ lmh,
    float* __restrict__ ws, float* __restrict__ logits, float* __restrict__ kvc)
{
    __shared__ float smem[2112];
    const int t = threadIdx.x;
    float* h    = ws;
    float* qkvb = ws + 2048;
    float* gub  = ws + 43008;
    int* flags  = (int*)(ws + FLAGS_OFF);

    for (int l = 0; l < 5; ++l) {
        const float* wq = Wq + (size_t)l * 1024 * 1024;
        const float* wk = Wk + (size_t)l * 1024 * 1024;
        const float* wv = Wv + (size_t)l * 1024 * 1024;
        const float* wo = Wo + (size_t)l * 1024 * 1024;
        const float* wg = Wg + (size_t)l * 1024 * 4096;
        const float* wu = Wu + (size_t)l * 1024 * 4096;
        const float* wd = Wd + (size_t)l * 4096 * 1024;
        float* qkv = qkvb + l * 6144;
        float* gu  = gub  + l * 16384;

        // QKV (384 tasks): waits on previous layer's down (512), or nothing for l=0
        phase_gemv<2, 8>(smem, t, h, ln1 + l * 1024, wq, wk, wv, 0,
                         qkv, 3072, 1024, 1024, 4, 32, 3,
                         flags, l ? 4 * (l - 1) + 3 : -1, 512, 4 * l);
        // attention + O-proj (512 tasks): waits on qkv (384)
        phase_attn_o(smem, t, qkv, qnw + l * 128, knw + l * 128, wo, h,
                     kvc + (size_t)(2 * l) * 2048,
                     flags, 4 * l, 384, 4 * l + 1);
        // gate & up (1024 tasks): waits on attn_o (512)
        phase_gemv<2, 8>(smem, t, h, ln2 + l * 1024, wg, wu, wu, 0,
                         gu, 8192, 4096, 4096, 16, 32, 2,
                         flags, 4 * l + 1, 512, 4 * l + 2);
        // down proj (512 tasks): waits on gate/up (1024)
        phase_down(smem, t, gu, wd, h, flags, 4 * l + 2, 1024, 4 * l + 3);
    }

    // lm heads + deferred final rmsnorm (3840 tasks): waits on last down (512)
    phase_gemv<1, 8>(smem, t, h + 1024, fnw, lmh, nullptr, nullptr,
                     (size_t)1024 * 2048, logits, 2048, 2048, 2048,
                     8, 32, 15, flags, 19, 512, 20);
}

extern "C" void kernel_launch(void* const* d_in, const int* in_sizes, int n_in,
                              void* d_out, int out_size, void* d_ws, size_t ws_size,
                              hipStream_t stream)
{
    const float* past_hidden = (const float*)d_in[0];
    const int*   cb0         = (const int*)d_in[1];
    const float* codec_emb   = (const float*)d_in[2];
    const float* Wq  = (const float*)d_in[3];
    const float* Wk  = (const float*)d_in[4];
    const float* Wv  = (const float*)d_in[5];
    const float* Wo  = (const float*)d_in[6];
    const float* qnw = (const float*)d_in[7];
    const float* knw = (const float*)d_in[8];
    const float* ln1 = (const float*)d_in[9];
    const float* ln2 = (const float*)d_in[10];
    const float* Wg  = (const float*)d_in[11];
    const float* Wu  = (const float*)d_in[12];
    const float* Wd  = (const float*)d_in[13];
    const float* fnw = (const float*)d_in[14];
    const float* lmh = (const float*)d_in[15];

    float* ws     = (float*)d_ws;
    float* logits = (float*)d_out;
    float* kvc    = (float*)d_out + 30720;

    init_kernel<<<256, 256, 0, stream>>>(past_hidden, codec_emb, cb0, ws, logits);

    // all blocks must be co-resident (flag protocol); cooperative launch validates.
    static int nblk = 0;
    if (nblk == 0) {
        int perCU = 0;
        if (hipOccupancyMaxActiveBlocksPerMultiprocessor(&perCU, net_kernel, 256, 0) != hipSuccess
            || perCU < 1) perCU = 1;
        nblk = perCU * 256;
        if (nblk > 1024) nblk = 1024;
        if (nblk < 256) nblk = 256;
    }

    void* args[] = {
        (void*)&Wq, (void*)&Wk, (void*)&Wv, (void*)&Wo,
        (void*)&qnw, (void*)&knw, (void*)&ln1, (void*)&ln2,
        (void*)&Wg, (void*)&Wu, (void*)&Wd, (void*)&fnw, (void*)&lmh,
        (void*)&ws, (void*)&logits, (void*)&kvc
    };
    hipLaunchCooperativeKernel((void*)net_kernel, dim3(nblk), dim3(256),
                               args, 0, stream);
}

// Round 5
// 566.088 us; speedup vs baseline: 1.8716x; 1.3075x over previous
//
#include <hip/hip_runtime.h>
#include <math.h>

#define EPS 1e-6f
#define FLAGS_OFF 32768    // int flags at ws + FLAGS_OFF (floats); 20 phases x 256 ints

// ws layout (floats):
//   h      @ 0       [2][1024]            (in-place residual accumulation, atomics only)
//   qkv    @ 2048    5 layers x [2][3072]
//   flags  @ 32768   20 x 256 ints (16 sub-counters x 16-int stride, one 64B line each)
//   gu     @ 43008   5 layers x [2][2][4096]

// Coherence-point load (agent scope): always fresh across XCDs, never cached stale.
__device__ __forceinline__ float ato(const float* p) {
    return __hip_atomic_load(p, __ATOMIC_RELAXED, __HIP_MEMORY_SCOPE_AGENT);
}

__device__ __forceinline__ float red32(float v) {
#pragma unroll
    for (int m = 16; m >= 1; m >>= 1) v += __shfl_xor(v, m, 64);
    return v;
}

// Consumer: wave 0 polls the 16 sub-counters of phase p in parallel.
__device__ __forceinline__ void spin_wait(int* flags, int p, int need, int t) {
    if (t < 64) {
        int* base = flags + p * 256;
        while (true) {
            int v = (t < 16) ? __hip_atomic_load(base + t * 16, __ATOMIC_RELAXED,
                                                 __HIP_MEMORY_SCOPE_AGENT) : 0;
#pragma unroll
            for (int m = 8; m >= 1; m >>= 1) v += __shfl_xor(v, m, 64);
            v = __shfl(v, 0, 64);
            if (v >= need) break;
            __builtin_amdgcn_s_sleep(4);
        }
    }
    __syncthreads();
}

// Producer: drain output atomics (vmcnt), block barrier, bump this block's sub-counter.
__device__ __forceinline__ void task_done(int* flags, int p, int t) {
    asm volatile("s_waitcnt vmcnt(0)" ::: "memory");
    __syncthreads();
    if (t == 0)
        __hip_atomic_fetch_add(flags + p * 256 + (blockIdx.x & 15) * 16, 1,
                               __ATOMIC_RELAXED, __HIP_MEMORY_SCOPE_AGENT);
}

// ---------------- init: zero accumulators + flags, build h ----------------
__global__ void init_kernel(const float* __restrict__ past_hidden,
                            const float* __restrict__ codec_emb,
                            const int* __restrict__ tok,
                            float* __restrict__ ws,
                            float* __restrict__ logits)
{
    size_t idx = (size_t)blockIdx.x * blockDim.x + threadIdx.x;
    size_t stride = (size_t)gridDim.x * blockDim.x;
    for (size_t i = idx; i < 30720; i += stride) ws[2048 + i] = 0.f;   // qkv x5
    for (size_t i = idx; i < 81920; i += stride) ws[43008 + i] = 0.f;  // gu x5
    for (size_t i = idx; i < 30720; i += stride) logits[i] = 0.f;
    int* flags = (int*)(ws + FLAGS_OFF);
    for (size_t i = idx; i < 20 * 256; i += stride) flags[i] = 0;
    int t = tok[0];
    for (size_t i = idx; i < 1024; i += stride) {
        ws[i]        = past_hidden[i];
        ws[1024 + i] = codec_emb[(size_t)t * 1024 + i];
    }
}

// ---------------- split-K GEMV phase, deferred RMSNorm, flag-synced, rotated ----------------
// out[z][s][Nslice] += rsqrt(mean(x^2)+eps) * ((x*nw) @ W) ; D = 1024.
// Task i of this phase runs on block (start + i) % nblk.
template <int S, int R>
__device__ void phase_gemv(
    float* smem, int t,
    const float* __restrict__ hbuf,   // [S][1024], read via ato()
    const float* __restrict__ nw,     // [1024]
    const float* __restrict__ W0, const float* __restrict__ W1,
    const float* __restrict__ W2, size_t w_zstride,
    float* __restrict__ out, int out_sstride, size_t out_zstride, int N,
    int nx, int ny, int nz,
    int* flags, int widx, int wneed, int didx, int start, int nblk)
{
    float* xs = smem;                 // S*1024, reused as reduction scratch
    float* sstot = smem + S * 1024;   // S*4
    const int lane = t & 63;
    const int dp = t >> 6;
    const int ntask = nx * ny * nz;
    bool waited = (widx < 0);

    for (int task = (blockIdx.x - start + 2 * nblk) % nblk; task < ntask; task += nblk) {
        const int z = task / (nx * ny);
        const int rem = task - z * (nx * ny);
        const int by = rem / nx;
        const int bx = rem - by * nx;

        const float* W;
        if (W1) W = (z == 0) ? W0 : ((z == 1) ? W1 : W2);
        else    W = W0 + (size_t)z * w_zstride;
        float* outz = out + (size_t)z * out_zstride;

        const int j = bx * 256 + lane * 4;
        const int d0 = by * (4 * R) + dp * R;

        // 1) issue weight prefetch BEFORE waiting on the dependency
        float4 wreg[R];
        const float* Wp = W + (size_t)d0 * N + j;
#pragma unroll
        for (int i = 0; i < R; ++i)
            wreg[i] = *reinterpret_cast<const float4*>(Wp + (size_t)i * N);

        if (!waited) { spin_wait(flags, widx, wneed, t); waited = true; }

        // 2) gather x at the coherence point, apply nw, keep sum-of-squares
        float ss[S];
        {
            float4 nw4 = *reinterpret_cast<const float4*>(nw + t * 4);
#pragma unroll
            for (int s = 0; s < S; ++s) {
                float x0 = ato(hbuf + s * 1024 + t * 4 + 0);
                float x1 = ato(hbuf + s * 1024 + t * 4 + 1);
                float x2 = ato(hbuf + s * 1024 + t * 4 + 2);
                float x3 = ato(hbuf + s * 1024 + t * 4 + 3);
                ss[s] = x0 * x0 + x1 * x1 + x2 * x2 + x3 * x3;
                xs[s * 1024 + t * 4 + 0] = x0 * nw4.x;
                xs[s * 1024 + t * 4 + 1] = x1 * nw4.y;
                xs[s * 1024 + t * 4 + 2] = x2 * nw4.z;
                xs[s * 1024 + t * 4 + 3] = x3 * nw4.w;
            }
        }
        __syncthreads();

        // 3) dot product
        float acc[S][4];
#pragma unroll
        for (int s = 0; s < S; ++s) { acc[s][0] = acc[s][1] = acc[s][2] = acc[s][3] = 0.f; }
#pragma unroll
        for (int i = 0; i < R; ++i) {
            int dd = d0 + i;
#pragma unroll
            for (int s = 0; s < S; ++s) {
                float xv = xs[s * 1024 + dd];
                acc[s][0] += xv * wreg[i].x; acc[s][1] += xv * wreg[i].y;
                acc[s][2] += xv * wreg[i].z; acc[s][3] += xv * wreg[i].w;
            }
        }

        // 4) finish rmsnorm sum (shuffle only)
#pragma unroll
        for (int s = 0; s < S; ++s) {
            float v = ss[s];
#pragma unroll
            for (int m = 32; m >= 1; m >>= 1) v += __shfl_xor(v, m, 64);
            if (lane == 0) sstot[s * 4 + dp] = v;
        }
        __syncthreads();
        float sc[S];
#pragma unroll
        for (int s = 0; s < S; ++s) {
            float tot = sstot[s * 4 + 0] + sstot[s * 4 + 1] + sstot[s * 4 + 2] + sstot[s * 4 + 3];
            sc[s] = rsqrtf(tot / 1024.f + EPS);
        }

        // 5) cross-dp reduce + atomic add
#pragma unroll
        for (int s = 0; s < S; ++s)
#pragma unroll
            for (int c = 0; c < 4; ++c)
                xs[(dp * S + s) * 256 + lane * 4 + c] = acc[s][c] * sc[s];
        __syncthreads();
        for (int o = t; o < S * 256; o += 256) {
            int s = o >> 8;
            int col = o & 255;
            float sum = 0.f;
#pragma unroll
            for (int p = 0; p < 4; ++p) sum += xs[(p * S + s) * 256 + col];
            atomicAdd(outz + (size_t)s * out_sstride + bx * 256 + col, sum);
        }
        if (didx >= 0) task_done(flags, didx, t);
        else __syncthreads();   // protect xs scratch before next task restages
    }
}

// ---------------- fused attention + O-projection phase (512 tasks, rotated) ----------------
__device__ void phase_attn_o(
    float* smem, int t,
    const float* __restrict__ qkv, const float* __restrict__ qnw,
    const float* __restrict__ knw, const float* __restrict__ W,
    float* __restrict__ out, float* __restrict__ kvc,
    int* flags, int widx, int wneed, int didx, int start, int nblk)
{
    float* xs = smem;                // 2048
    const int lane = t & 63;
    const int dp = t >> 6;
    bool waited = false;

    for (int task = (blockIdx.x - start + 2 * nblk) % nblk; task < 512; task += nblk) {
        const int bx = task & 3;
        const int by = task >> 2;
        const int j = bx * 256 + lane * 4;
        const int d0 = by * 8 + dp * 2;

        float4 wreg[2];
        const float* Wp = W + (size_t)d0 * 1024 + j;
        wreg[0] = *reinterpret_cast<const float4*>(Wp);
        wreg[1] = *reinterpret_cast<const float4*>(Wp + 1024);

        if (!waited) { spin_wait(flags, widx, wneed, t); waited = true; }

        const int hh = t >> 5;
        const int g = t & 31;
        float q[2][4], k[2][4], v[2][4];
#pragma unroll
        for (int s = 0; s < 2; ++s)
#pragma unroll
            for (int c = 0; c < 4; ++c) {
                int d = g + c * 32;
                q[s][c] = ato(qkv + s * 3072 +        hh * 128 + d);
                k[s][c] = ato(qkv + s * 3072 + 1024 + hh * 128 + d);
                v[s][c] = ato(qkv + s * 3072 + 2048 + hh * 128 + d);
            }
#pragma unroll
        for (int s = 0; s < 2; ++s) {
            float sq = q[s][0]*q[s][0] + q[s][1]*q[s][1] + q[s][2]*q[s][2] + q[s][3]*q[s][3];
            float sk = k[s][0]*k[s][0] + k[s][1]*k[s][1] + k[s][2]*k[s][2] + k[s][3]*k[s][3];
            sq = red32(sq); sk = red32(sk);
            float qsc = rsqrtf(sq / 128.f + EPS);
            float ksc = rsqrtf(sk / 128.f + EPS);
#pragma unroll
            for (int c = 0; c < 4; ++c) {
                q[s][c] *= qsc * qnw[g + c * 32];
                k[s][c] *= ksc * knw[g + c * 32];
            }
        }
        float inv0 = powf(10000.f, -(float)g / 64.f);
        float inv1 = powf(10000.f, -(float)(g + 32) / 64.f);
        float cA = cosf(inv0), sA = sinf(inv0);
        float cB = cosf(inv1), sB = sinf(inv1);
        float q1[4] = { q[1][0]*cA - q[1][2]*sA, q[1][1]*cB - q[1][3]*sB,
                        q[1][2]*cA + q[1][0]*sA, q[1][3]*cB + q[1][1]*sB };
        float k1[4] = { k[1][0]*cA - k[1][2]*sA, k[1][1]*cB - k[1][3]*sB,
                        k[1][2]*cA + k[1][0]*sA, k[1][3]*cB + k[1][1]*sB };

        if (task == 0) {
#pragma unroll
            for (int c = 0; c < 4; ++c) {
                int d = g + c * 32;
                kvc[hh * 256 +       d] = k[0][c];
                kvc[hh * 256 + 128 + d] = k1[c];
                kvc[2048 + hh * 256 +       d] = v[0][c];
                kvc[2048 + hh * 256 + 128 + d] = v[1][c];
            }
        }

        float p00 = red32(q[0][0]*k[0][0] + q[0][1]*k[0][1] + q[0][2]*k[0][2] + q[0][3]*k[0][3]);
        float p01 = red32(q[0][0]*k1[0]   + q[0][1]*k1[1]   + q[0][2]*k1[2]   + q[0][3]*k1[3]);
        float p10 = red32(q1[0]*k[0][0]   + q1[1]*k[0][1]   + q1[2]*k[0][2]   + q1[3]*k[0][3]);
        float p11 = red32(q1[0]*k1[0]     + q1[1]*k1[1]     + q1[2]*k1[2]     + q1[3]*k1[3]);

        const float scale = 0.08838834764831845f; // 1/sqrt(128)
        float s00 = p00 * scale, s01 = p01 * scale - 1e9f;
        float m0 = fmaxf(s00, s01);
        float e0 = expf(s00 - m0), e1 = expf(s01 - m0);
        float in0 = 1.f / (e0 + e1);
        float w00 = e0 * in0, w01 = e1 * in0;
        float s10 = p10 * scale, s11 = p11 * scale;
        float m1 = fmaxf(s10, s11);
        float f0 = expf(s10 - m1), f1 = expf(s11 - m1);
        float in1 = 1.f / (f0 + f1);
        float w10 = f0 * in1, w11 = f1 * in1;

#pragma unroll
        for (int c = 0; c < 4; ++c) {
            int d = g + c * 32;
            xs[       hh * 128 + d] = w00 * v[0][c] + w01 * v[1][c];
            xs[1024 + hh * 128 + d] = w10 * v[0][c] + w11 * v[1][c];
        }
        __syncthreads();

        float acc[2][4] = {{0.f,0.f,0.f,0.f},{0.f,0.f,0.f,0.f}};
#pragma unroll
        for (int i = 0; i < 2; ++i) {
            int dd = d0 + i;
#pragma unroll
            for (int s = 0; s < 2; ++s) {
                float xv = xs[s * 1024 + dd];
                acc[s][0] += xv * wreg[i].x; acc[s][1] += xv * wreg[i].y;
                acc[s][2] += xv * wreg[i].z; acc[s][3] += xv * wreg[i].w;
            }
        }
        __syncthreads();
#pragma unroll
        for (int s = 0; s < 2; ++s)
#pragma unroll
            for (int c = 0; c < 4; ++c)
                xs[(dp * 2 + s) * 256 + lane * 4 + c] = acc[s][c];
        __syncthreads();
        for (int o = t; o < 512; o += 256) {
            int s = o >> 8, col = o & 255;
            float sum = 0.f;
#pragma unroll
            for (int p = 0; p < 4; ++p) sum += xs[(p * 2 + s) * 256 + col];
            atomicAdd(out + (size_t)s * 1024 + bx * 256 + col, sum);
        }
        task_done(flags, didx, t);
    }
}

// ---------------- down-proj phase with fused silu(gate)*up (512 tasks, rotated) ----------------
__device__ void phase_down(
    float* smem, int t,
    const float* __restrict__ gu, const float* __restrict__ W,
    float* __restrict__ out,
    int* flags, int widx, int wneed, int didx, int start, int nblk)
{
    float* red = smem;             // 2048
    float* a   = smem + 2048;      // 2*32
    const int lane = t & 63;
    const int dp = t >> 6;
    bool waited = false;

    for (int task = (blockIdx.x - start + 2 * nblk) % nblk; task < 512; task += nblk) {
        const int bx = task & 3;
        const int by = task >> 2;
        const int j = bx * 256 + lane * 4;
        const int f0 = by * 32 + dp * 8;

        float4 wreg[8];
        const float* Wp = W + (size_t)f0 * 1024 + j;
#pragma unroll
        for (int i = 0; i < 8; ++i)
            wreg[i] = *reinterpret_cast<const float4*>(Wp + (size_t)i * 1024);

        if (!waited) { spin_wait(flags, widx, wneed, t); waited = true; }

        if (t < 64) {
            int s = t >> 5, x = t & 31;
            int f = by * 32 + x;
            float g = ato(gu + s * 8192 + f);
            float u = ato(gu + s * 8192 + 4096 + f);
            a[s * 32 + x] = g / (1.f + expf(-g)) * u;
        }
        __syncthreads();

        float acc[2][4] = {{0.f,0.f,0.f,0.f},{0.f,0.f,0.f,0.f}};
#pragma unroll
        for (int i = 0; i < 8; ++i) {
            int dl = dp * 8 + i;
#pragma unroll
            for (int s = 0; s < 2; ++s) {
                float xv = a[s * 32 + dl];
                acc[s][0] += xv * wreg[i].x; acc[s][1] += xv * wreg[i].y;
                acc[s][2] += xv * wreg[i].z; acc[s][3] += xv * wreg[i].w;
            }
        }
        __syncthreads();
#pragma unroll
        for (int s = 0; s < 2; ++s)
#pragma unroll
            for (int c = 0; c < 4; ++c)
                red[(dp * 2 + s) * 256 + lane * 4 + c] = acc[s][c];
        __syncthreads();
        for (int o = t; o < 512; o += 256) {
            int s = o >> 8, col = o & 255;
            float sum = 0.f;
#pragma unroll
            for (int p = 0; p < 4; ++p) sum += red[(p * 2 + s) * 256 + col];
            atomicAdd(out + (size_t)s * 1024 + bx * 256 + col, sum);
        }
        task_done(flags, didx, t);
    }
}

// ---------------- whole network, one persistent kernel, rotated flag pipeline ----------------
__global__ __launch_bounds__(256, 4) void net_kernel(
    const float* __restrict__ Wq, const float* __restrict__ Wk,
    const float* __restrict__ Wv, const float* __restrict__ Wo,
    const float* __restrict__ qnw, const float* __restrict__ knw,
    const float* __restrict__ ln1, const float* __restrict__ ln2,
    const float* __restrict__ Wg, const float* __restrict__ Wu,
    const float* __restrict__ Wd, const float* __restrict__ fnw,
    const float* __restrict__ lmh,
    float* __restrict__ ws, float* __restrict__ logits, float* __restrict__ kvc)
{
    __shared__ float smem[2112];
    const int t = threadIdx.x;
    const int nblk = gridDim.x;
    float* h    = ws;
    float* qkvb = ws + 2048;
    float* gub  = ws + 43008;
    int* flags  = (int*)(ws + FLAGS_OFF);
    int off = 0;

    for (int l = 0; l < 5; ++l) {
        const float* wq = Wq + (size_t)l * 1024 * 1024;
        const float* wk = Wk + (size_t)l * 1024 * 1024;
        const float* wv = Wv + (size_t)l * 1024 * 1024;
        const float* wo = Wo + (size_t)l * 1024 * 1024;
        const float* wg = Wg + (size_t)l * 1024 * 4096;
        const float* wu = Wu + (size_t)l * 1024 * 4096;
        const float* wd = Wd + (size_t)l * 4096 * 1024;
        float* qkv = qkvb + l * 6144;
        float* gu  = gub  + l * 16384;
        int st;

        // QKV (384 tasks): waits on previous layer's down (512), or nothing for l=0
        st = off % nblk; off += 384;
        phase_gemv<2, 8>(smem, t, h, ln1 + l * 1024, wq, wk, wv, 0,
                         qkv, 3072, 1024, 1024, 4, 32, 3,
                         flags, l ? 4 * (l - 1) + 3 : -1, 512, 4 * l, st, nblk);
        // attention + O-proj (512 tasks): waits on qkv (384)
        st = off % nblk; off += 512;
        phase_attn_o(smem, t, qkv, qnw + l * 128, knw + l * 128, wo, h,
                     kvc + (size_t)(2 * l) * 2048,
                     flags, 4 * l, 384, 4 * l + 1, st, nblk);
        // gate & up (512 tasks, R=16): waits on attn_o (512)
        st = off % nblk; off += 512;
        phase_gemv<2, 16>(smem, t, h, ln2 + l * 1024, wg, wu, wu, 0,
                          gu, 8192, 4096, 4096, 16, 16, 2,
                          flags, 4 * l + 1, 512, 4 * l + 2, st, nblk);
        // down proj (512 tasks): waits on gate/up (512)
        st = off % nblk; off += 512;
        phase_down(smem, t, gu, wd, h, flags, 4 * l + 2, 512, 4 * l + 3, st, nblk);
    }

    // lm heads + deferred final rmsnorm (1920 tasks, R=16): waits on last down (512)
    int st = off % nblk;
    phase_gemv<1, 16>(smem, t, h + 1024, fnw, lmh, nullptr, nullptr,
                      (size_t)1024 * 2048, logits, 2048, 2048, 2048,
                      8, 16, 15, flags, 19, 512, -1, st, nblk);
}

extern "C" void kernel_launch(void* const* d_in, const int* in_sizes, int n_in,
                              void* d_out, int out_size, void* d_ws, size_t ws_size,
                              hipStream_t stream)
{
    const float* past_hidden = (const float*)d_in[0];
    const int*   cb0         = (const int*)d_in[1];
    const float* codec_emb   = (const float*)d_in[2];
    const float* Wq  = (const float*)d_in[3];
    const float* Wk  = (const float*)d_in[4];
    const float* Wv  = (const float*)d_in[5];
    const float* Wo  = (const float*)d_in[6];
    const float* qnw = (const float*)d_in[7];
    const float* knw = (const float*)d_in[8];
    const float* ln1 = (const float*)d_in[9];
    const float* ln2 = (const float*)d_in[10];
    const float* Wg  = (const float*)d_in[11];
    const float* Wu  = (const float*)d_in[12];
    const float* Wd  = (const float*)d_in[13];
    const float* fnw = (const float*)d_in[14];
    const float* lmh = (const float*)d_in[15];

    float* ws     = (float*)d_ws;
    float* logits = (float*)d_out;
    float* kvc    = (float*)d_out + 30720;

    init_kernel<<<128, 256, 0, stream>>>(past_hidden, codec_emb, cb0, ws, logits);

    // all blocks must be co-resident (flag protocol); cooperative launch validates.
    static int nblk = 0;
    if (nblk == 0) {
        int perCU = 0;
        if (hipOccupancyMaxActiveBlocksPerMultiprocessor(&perCU, net_kernel, 256, 0) != hipSuccess
            || perCU < 1) perCU = 1;
        nblk = perCU * 256;
        if (nblk > 1024) nblk = 1024;
        if (nblk < 256) nblk = 256;
    }

    void* args[] = {
        (void*)&Wq, (void*)&Wk, (void*)&Wv, (void*)&Wo,
        (void*)&qnw, (void*)&knw, (void*)&ln1, (void*)&ln2,
        (void*)&Wg, (void*)&Wu, (void*)&Wd, (void*)&fnw, (void*)&lmh,
        (void*)&ws, (void*)&logits, (void*)&kvc
    };
    hipLaunchCooperativeKernel((void*)net_kernel, dim3(nblk), dim3(256),
                               args, 0, stream);
}